// Round 1
// baseline (500.018 us; speedup 1.0000x reference)
//
#include <hip/hip_runtime.h>
#include <hip/hip_bf16.h>

typedef unsigned short u16;
typedef __attribute__((ext_vector_type(8))) short bf16x8;   // 8 bf16 = 4 VGPRs
typedef __attribute__((ext_vector_type(4))) float f32x4;

#define EPSN 1e-9f

// ---------- helpers ----------

__device__ __forceinline__ u16 f2bf(float f) {
    union { float f; unsigned int u; } c; c.f = f;
    unsigned int u = c.u;
    unsigned int r = (u + 0x7FFFu + ((u >> 16) & 1u)) >> 16;   // RNE
    return (u16)r;
}

__device__ __forceinline__ void load16_to_lds(const void* g, void* l) {
    __builtin_amdgcn_global_load_lds(
        (const __attribute__((address_space(1))) void*)g,
        (__attribute__((address_space(3))) void*)l,
        16, 0, 0);
}

// ---------- K1/K2: per-row L2 normalize + cast to bf16 ----------
// one block (256 thr) per row; ncols multiple of 4
__global__ __launch_bounds__(256) void normalize_cast(
    const float* __restrict__ X, u16* __restrict__ Y, int ncols) {
    const size_t row = blockIdx.x;
    const float4* xr = (const float4*)(X + row * (size_t)ncols);
    const int nq = ncols >> 2;

    float ss = 0.f;
    for (int i = threadIdx.x; i < nq; i += 256) {
        float4 v = xr[i];
        ss += v.x*v.x + v.y*v.y + v.z*v.z + v.w*v.w;
    }
    #pragma unroll
    for (int o = 32; o > 0; o >>= 1) ss += __shfl_down(ss, o);

    __shared__ float red[4];
    __shared__ float scale_sh;
    const int lane = threadIdx.x & 63, wv = threadIdx.x >> 6;
    if (lane == 0) red[wv] = ss;
    __syncthreads();
    if (threadIdx.x == 0) {
        float t = red[0] + red[1] + red[2] + red[3];
        scale_sh = 1.f / (sqrtf(t) + EPSN);
    }
    __syncthreads();
    const float s = scale_sh;

    ushort4* yr = (ushort4*)(Y + row * (size_t)ncols);
    for (int i = threadIdx.x; i < nq; i += 256) {
        float4 v = xr[i];
        ushort4 o4;
        o4.x = f2bf(v.x * s); o4.y = f2bf(v.y * s);
        o4.z = f2bf(v.z * s); o4.w = f2bf(v.w * s);
        yr[i] = o4;
    }
}

// ---------- tiny: exp(logprior) ----------
__global__ void prep_explp(const float* __restrict__ lp, float* __restrict__ out, int n) {
    int i = blockIdx.x * blockDim.x + threadIdx.x;
    if (i < n) out[i] = expf(lp[i]);
}

// ---------- K3: bf16 MFMA GEMM (A[M,K] * B[N,K]^T) + fused relu/pow epilogue ----------
// 128x128 tile, BK=64, 4 waves each computing 64x64 via 4x4 grid of 16x16x32 MFMA.
// LDS XOR-swizzle: chunk (row, kc) of 8 bf16 stored at position kc ^ (row&7)
// -> global_load_lds stays contiguous (base + lane*16), ds_read_b128 is 2-way max.
#define BK 64

__global__ __launch_bounds__(256, 1) void gemm_softhebb(
    const u16* __restrict__ A, const u16* __restrict__ B,
    const float* __restrict__ explp, const float* __restrict__ lambp,
    float* __restrict__ Ul, float* __restrict__ rowsum,
    int M, int N, int K) {
    __shared__ __align__(16) u16 lA[128 * BK];
    __shared__ __align__(16) u16 lB[128 * BK];

    const int tid  = threadIdx.x;
    const int lane = tid & 63;
    const int wm   = (tid >> 6) & 1;   // wave row (0..1)
    const int wn   = tid >> 7;         // wave col (0..1)
    const int row0 = blockIdx.y * 128;
    const int col0 = blockIdx.x * 128;

    const u16* Ag = A + (size_t)row0 * K;
    const u16* Bg = B + (size_t)col0 * K;

    f32x4 acc[4][4] = {};

    // staging indices: chunk c = p*256+tid; row=c>>3, stored pos=c&7,
    // global kchunk = (c&7) ^ (row&7)
    int srow[4], soff[4];
    #pragma unroll
    for (int p = 0; p < 4; ++p) {
        int c = p * 256 + tid;
        int r = c >> 3;
        srow[p] = r;
        soff[p] = ((c & 7) ^ (r & 7)) * 8;
    }

    for (int k0 = 0; k0 < K; k0 += BK) {
        #pragma unroll
        for (int p = 0; p < 4; ++p) {
            int c = p * 256 + tid;
            load16_to_lds(Ag + (size_t)srow[p] * K + k0 + soff[p], &lA[c * 8]);
            load16_to_lds(Bg + (size_t)srow[p] * K + k0 + soff[p], &lB[c * 8]);
        }
        __syncthreads();

        #pragma unroll
        for (int s = 0; s < 2; ++s) {
            // fragment row r has (r&7)==(lane&7); kchunk = s*4 + (lane>>4)
            const int pos = (((s << 2) + (lane >> 4)) ^ (lane & 7)) * 8;
            bf16x8 af[4], bfr[4];
            #pragma unroll
            for (int i = 0; i < 4; ++i) {
                int r = wm * 64 + i * 16 + (lane & 15);
                af[i] = *(const bf16x8*)&lA[r * 64 + pos];
            }
            #pragma unroll
            for (int j = 0; j < 4; ++j) {
                int r = wn * 64 + j * 16 + (lane & 15);
                bfr[j] = *(const bf16x8*)&lB[r * 64 + pos];
            }
            #pragma unroll
            for (int i = 0; i < 4; ++i)
                #pragma unroll
                for (int j = 0; j < 4; ++j)
                    acc[i][j] = __builtin_amdgcn_mfma_f32_16x16x32_bf16(
                        af[i], bfr[j], acc[i][j], 0, 0, 0);
        }
        __syncthreads();
    }

    // epilogue: u = relu(a); ul = u^lam * exp(logprior); write + row partial sums
    // C/D layout: col = lane&15, row = (lane>>4)*4 + p   [m89/m91 verified]
    const float lam = *lambp;
    const bool lam4 = (lam == 4.0f);
    #pragma unroll
    for (int i = 0; i < 4; ++i) {
        #pragma unroll
        for (int p = 0; p < 4; ++p) {
            const int m = row0 + wm * 64 + i * 16 + (lane >> 4) * 4 + p;
            float rs = 0.f;
            #pragma unroll
            for (int j = 0; j < 4; ++j) {
                const int n = col0 + wn * 64 + j * 16 + (lane & 15);
                float a = acc[i][j][p];
                float u = 0.f;
                if (a > 0.f) {
                    float pw;
                    if (lam4) { float a2 = a * a; pw = a2 * a2; }
                    else      { pw = __powf(a, lam); }
                    u = pw * explp[n];
                }
                Ul[(size_t)m * N + n] = u;
                rs += u;
            }
            // reduce across the 16 lanes sharing this row (lanes differ in low 4 bits)
            rs += __shfl_xor(rs, 1);
            rs += __shfl_xor(rs, 2);
            rs += __shfl_xor(rs, 4);
            rs += __shfl_xor(rs, 8);
            if ((lane & 15) == 0) atomicAdd(&rowsum[m], rs);
        }
    }
}

// ---------- K4: y = ul / (rowsum + eps) in place ----------
__global__ __launch_bounds__(256) void finalize_div(
    float* __restrict__ Ul, const float* __restrict__ rowsum,
    int nq_per_row, long total_q) {
    long i = (long)blockIdx.x * blockDim.x + threadIdx.x;
    const long stride = (long)gridDim.x * blockDim.x;
    for (; i < total_q; i += stride) {
        int row = (int)(i / nq_per_row);
        float inv = 1.f / (rowsum[row] + EPSN);
        float4 v = ((const float4*)Ul)[i];
        v.x *= inv; v.y *= inv; v.z *= inv; v.w *= inv;
        ((float4*)Ul)[i] = v;
    }
}

// ---------- launch ----------
static inline size_t align256(size_t x) { return (x + 255) & ~(size_t)255; }

extern "C" void kernel_launch(void* const* d_in, const int* in_sizes, int n_in,
                              void* d_out, int out_size, void* d_ws, size_t ws_size,
                              hipStream_t stream) {
    const float* x        = (const float*)d_in[0];
    const float* w        = (const float*)d_in[1];
    const float* logprior = (const float*)d_in[2];
    const float* lamb     = (const float*)d_in[3];
    const int OUT = in_sizes[2];                // 2048
    const int IN  = in_sizes[1] / OUT;          // 2048
    const int B   = in_sizes[0] / IN;           // 16384
    float* out = (float*)d_out;

    char* ws = (char*)d_ws;
    size_t off = 0;
    u16* xn = (u16*)(ws + off);        off += align256((size_t)B * IN * sizeof(u16));
    u16* wn = (u16*)(ws + off);        off += align256((size_t)OUT * IN * sizeof(u16));
    float* rowsum = (float*)(ws + off); off += align256((size_t)B * sizeof(float));
    float* explp  = (float*)(ws + off); off += align256((size_t)OUT * sizeof(float));

    hipMemsetAsync(rowsum, 0, (size_t)B * sizeof(float), stream);
    normalize_cast<<<B, 256, 0, stream>>>(x, xn, IN);
    normalize_cast<<<OUT, 256, 0, stream>>>(w, wn, IN);
    prep_explp<<<(OUT + 255) / 256, 256, 0, stream>>>(logprior, explp, OUT);

    dim3 grid(OUT / 128, B / 128);
    gemm_softhebb<<<grid, 256, 0, stream>>>(xn, wn, explp, lamb, out, rowsum, B, OUT, IN);

    long total_q = (long)B * OUT / 4;
    finalize_div<<<8192, 256, 0, stream>>>(out, rowsum, OUT / 4, total_q);
}

// Round 2
// 414.479 us; speedup vs baseline: 1.2064x; 1.2064x over previous
//
#include <hip/hip_runtime.h>
#include <hip/hip_bf16.h>

typedef unsigned short u16;
typedef __attribute__((ext_vector_type(8))) short bf16x8;   // 8 bf16 = 4 VGPRs
typedef __attribute__((ext_vector_type(4))) float f32x4;

#define EPSN 1e-9f

// ---------- helpers ----------

__device__ __forceinline__ u16 f2bf(float f) {
    union { float f; unsigned int u; } c; c.f = f;
    unsigned int u = c.u;
    unsigned int r = (u + 0x7FFFu + ((u >> 16) & 1u)) >> 16;   // RNE
    return (u16)r;
}

__device__ __forceinline__ void load16_to_lds(const void* g, void* l) {
    __builtin_amdgcn_global_load_lds(
        (const __attribute__((address_space(1))) void*)g,
        (__attribute__((address_space(3))) void*)l,
        16, 0, 0);
}

// ---------- K1/K2: per-row L2 normalize + cast to bf16 (single HBM read) ----------
// one block (256 thr) per row; row data held in registers between sumsq and scale.
// Supports ncols <= 8192 (MAXQ=8 float4 per thread); our shape uses 2.
#define MAXQ 8
__global__ __launch_bounds__(256) void normalize_cast(
    const float* __restrict__ X, u16* __restrict__ Y, int ncols) {
    const size_t row = blockIdx.x;
    const float4* xr = (const float4*)(X + row * (size_t)ncols);
    const int nq = ncols >> 2;

    float4 v[MAXQ];
    float ss = 0.f;
    #pragma unroll
    for (int k = 0; k < MAXQ; ++k) {
        int i = threadIdx.x + k * 256;
        if (i < nq) {
            v[k] = xr[i];
            ss += v[k].x*v[k].x + v[k].y*v[k].y + v[k].z*v[k].z + v[k].w*v[k].w;
        }
    }
    #pragma unroll
    for (int o = 32; o > 0; o >>= 1) ss += __shfl_down(ss, o);

    __shared__ float red[4];
    __shared__ float scale_sh;
    const int lane = threadIdx.x & 63, wv = threadIdx.x >> 6;
    if (lane == 0) red[wv] = ss;
    __syncthreads();
    if (threadIdx.x == 0) {
        float t = red[0] + red[1] + red[2] + red[3];
        scale_sh = 1.f / (sqrtf(t) + EPSN);
    }
    __syncthreads();
    const float s = scale_sh;

    ushort4* yr = (ushort4*)(Y + row * (size_t)ncols);
    #pragma unroll
    for (int k = 0; k < MAXQ; ++k) {
        int i = threadIdx.x + k * 256;
        if (i < nq) {
            ushort4 o4;
            o4.x = f2bf(v[k].x * s); o4.y = f2bf(v[k].y * s);
            o4.z = f2bf(v[k].z * s); o4.w = f2bf(v[k].w * s);
            yr[i] = o4;
        }
    }
}

// ---------- tiny: exp(logprior) ----------
__global__ void prep_explp(const float* __restrict__ lp, float* __restrict__ out, int n) {
    int i = blockIdx.x * blockDim.x + threadIdx.x;
    if (i < n) out[i] = expf(lp[i]);
}

// ---------- K3: bf16 MFMA GEMM (A[M,K] * B[N,K]^T) + fused relu/pow epilogue ----------
// 128x128 tile, BK=64, 4 waves each computing 64x64 via 4x4 grid of 16x16x32 MFMA.
// LDS XOR-swizzle: chunk (row, kc) of 8 bf16 stored at position kc ^ (row&7)
// -> global_load_lds stays contiguous (base + lane*16), ds_read_b128 is 2-way max.
#define BK 64

__global__ __launch_bounds__(256, 2) void gemm_softhebb(
    const u16* __restrict__ A, const u16* __restrict__ B,
    const float* __restrict__ explp, const float* __restrict__ lambp,
    float* __restrict__ Ul, float* __restrict__ rowsum,
    int M, int N, int K) {
    __shared__ __align__(16) u16 lA[128 * BK];
    __shared__ __align__(16) u16 lB[128 * BK];

    const int tid  = threadIdx.x;
    const int lane = tid & 63;
    const int wm   = (tid >> 6) & 1;   // wave row (0..1)
    const int wn   = tid >> 7;         // wave col (0..1)
    const int row0 = blockIdx.y * 128;
    const int col0 = blockIdx.x * 128;

    f32x4 acc[4][4] = {};

    // staging indices: chunk c = p*256+tid; row=c>>3, stored pos=c&7,
    // global kchunk = (c&7) ^ (row&7)
    const u16* ap[4];
    const u16* bp[4];
    #pragma unroll
    for (int p = 0; p < 4; ++p) {
        int c = p * 256 + tid;
        int r = c >> 3;
        int o = ((c & 7) ^ (r & 7)) * 8;
        ap[p] = A + (size_t)(row0 + r) * K + o;
        bp[p] = B + (size_t)(col0 + r) * K + o;
    }

    for (int k0 = 0; k0 < K; k0 += BK) {
        #pragma unroll
        for (int p = 0; p < 4; ++p) {
            int c = p * 256 + tid;
            load16_to_lds(ap[p] + k0, &lA[c * 8]);
            load16_to_lds(bp[p] + k0, &lB[c * 8]);
        }
        __syncthreads();

        #pragma unroll
        for (int s = 0; s < 2; ++s) {
            // fragment row r has (r&7)==(lane&7); kchunk = s*4 + (lane>>4)
            const int pos = (((s << 2) + (lane >> 4)) ^ (lane & 7)) * 8;
            bf16x8 af[4], bfr[4];
            #pragma unroll
            for (int i = 0; i < 4; ++i) {
                int r = wm * 64 + i * 16 + (lane & 15);
                af[i] = *(const bf16x8*)&lA[r * 64 + pos];
            }
            #pragma unroll
            for (int j = 0; j < 4; ++j) {
                int r = wn * 64 + j * 16 + (lane & 15);
                bfr[j] = *(const bf16x8*)&lB[r * 64 + pos];
            }
            #pragma unroll
            for (int i = 0; i < 4; ++i)
                #pragma unroll
                for (int j = 0; j < 4; ++j)
                    acc[i][j] = __builtin_amdgcn_mfma_f32_16x16x32_bf16(
                        af[i], bfr[j], acc[i][j], 0, 0, 0);
        }
        __syncthreads();
    }

    // epilogue: u = relu(a); ul = u^lam * exp(logprior); write + row partial sums
    // C/D layout: col = lane&15, row = (lane>>4)*4 + p   [m89/m91 verified]
    const float lam = *lambp;
    const bool lam4 = (lam == 4.0f);
    // hoist the 4 explp values this lane needs (col depends only on j)
    float el[4];
    #pragma unroll
    for (int j = 0; j < 4; ++j)
        el[j] = explp[col0 + wn * 64 + j * 16 + (lane & 15)];

    #pragma unroll
    for (int i = 0; i < 4; ++i) {
        #pragma unroll
        for (int p = 0; p < 4; ++p) {
            const int m = row0 + wm * 64 + i * 16 + (lane >> 4) * 4 + p;
            float* outrow = Ul + (size_t)m * N + col0 + wn * 64 + (lane & 15);
            float rs = 0.f;
            #pragma unroll
            for (int j = 0; j < 4; ++j) {
                float a = acc[i][j][p];
                float u = 0.f;
                if (a > 0.f) {
                    float pw;
                    if (lam4) { float a2 = a * a; pw = a2 * a2; }
                    else      { pw = __powf(a, lam); }
                    u = pw * el[j];
                }
                outrow[j * 16] = u;
                rs += u;
            }
            // reduce across the 16 lanes sharing this row (lanes differ in low 4 bits)
            rs += __shfl_xor(rs, 1);
            rs += __shfl_xor(rs, 2);
            rs += __shfl_xor(rs, 4);
            rs += __shfl_xor(rs, 8);
            if ((lane & 15) == 0) atomicAdd(&rowsum[m], rs);
        }
    }
}

// ---------- K4: y = ul / (rowsum + eps), one block per row (no int division) ----------
__global__ __launch_bounds__(256) void finalize_row(
    float* __restrict__ Ul, const float* __restrict__ rowsum, int nq) {
    const size_t row = blockIdx.x;
    const float inv = 1.f / (rowsum[row] + EPSN);
    float4* p = (float4*)(Ul + row * (size_t)nq * 4);
    for (int i = threadIdx.x; i < nq; i += 256) {
        float4 v = p[i];
        v.x *= inv; v.y *= inv; v.z *= inv; v.w *= inv;
        p[i] = v;
    }
}

// ---------- launch ----------
static inline size_t align256(size_t x) { return (x + 255) & ~(size_t)255; }

extern "C" void kernel_launch(void* const* d_in, const int* in_sizes, int n_in,
                              void* d_out, int out_size, void* d_ws, size_t ws_size,
                              hipStream_t stream) {
    const float* x        = (const float*)d_in[0];
    const float* w        = (const float*)d_in[1];
    const float* logprior = (const float*)d_in[2];
    const float* lamb     = (const float*)d_in[3];
    const int OUT = in_sizes[2];                // 2048
    const int IN  = in_sizes[1] / OUT;          // 2048
    const int B   = in_sizes[0] / IN;           // 16384
    float* out = (float*)d_out;

    char* ws = (char*)d_ws;
    size_t off = 0;
    u16* xn = (u16*)(ws + off);        off += align256((size_t)B * IN * sizeof(u16));
    u16* wn = (u16*)(ws + off);        off += align256((size_t)OUT * IN * sizeof(u16));
    float* rowsum = (float*)(ws + off); off += align256((size_t)B * sizeof(float));
    float* explp  = (float*)(ws + off); off += align256((size_t)OUT * sizeof(float));

    hipMemsetAsync(rowsum, 0, (size_t)B * sizeof(float), stream);
    normalize_cast<<<B, 256, 0, stream>>>(x, xn, IN);
    normalize_cast<<<OUT, 256, 0, stream>>>(w, wn, IN);
    prep_explp<<<(OUT + 255) / 256, 256, 0, stream>>>(logprior, explp, OUT);

    dim3 grid(OUT / 128, B / 128);
    gemm_softhebb<<<grid, 256, 0, stream>>>(xn, wn, explp, lamb, out, rowsum, B, OUT, IN);

    finalize_row<<<B, 256, 0, stream>>>(out, rowsum, OUT / 4);
}